// Round 4
// baseline (448.541 us; speedup 1.0000x reference)
//
#include <hip/hip_runtime.h>
#include <stdint.h>

#define BS   8
#define CH   256    // C
#define LSEQ 4096   // H*W
#define DIN  256    // INNER
#define NT   64     // number of KV tiles
#define KT   64     // kv rows per tile

typedef __bf16 bf16x8 __attribute__((ext_vector_type(8)));
typedef __bf16 bf16x4 __attribute__((ext_vector_type(4)));
typedef float  f32x4  __attribute__((ext_vector_type(4)));

// async global->LDS, 16B per lane; LDS dest = wave-uniform base + lane*16
__device__ __forceinline__ void gload_lds16(const void* g, void* l) {
    __builtin_amdgcn_global_load_lds(
        (const __attribute__((address_space(1))) uint32_t*)g,
        (__attribute__((address_space(3))) uint32_t*)l, 16, 0, 0);
}

// ---------------------------------------------------------------------------
// Kernel 1: QKV projection. Y[l][i] = sum_c X[c][l]*W[i][c] + b[i].
// which==0 -> Q linear [l][i] bf16.
// which==1 -> K into swizzled tile image: tile(b,kt) 32KB, byte =
//             row*512 + ((2i) ^ ((row&7)<<4)), row = l&63.
// which==2 -> V into tile image second half: byte = 32768 + d*128 +
//             ((2*(l&63)) ^ ((d&7)<<4)).
// KV tile = 64KB: [K img 32KB][V img 32KB], contiguous per (b,kt).
// ---------------------------------------------------------------------------
__global__ __launch_bounds__(256) void qkv_proj_kernel(
    const float* __restrict__ x,
    const float* __restrict__ Wq, const float* __restrict__ bq,
    const float* __restrict__ Wk, const float* __restrict__ bk,
    const float* __restrict__ Wv, const float* __restrict__ bv,
    __bf16* __restrict__ Q, uint8_t* __restrict__ KV)
{
    const int b     = blockIdx.z;
    const int which = blockIdx.y;
    const int l0    = blockIdx.x * 64;

    const float* W    = (which == 0) ? Wq : (which == 1) ? Wk : Wv;
    const float* bias = (which == 0) ? bq : (which == 1) ? bk : bv;
    const float* X    = x + (size_t)b * CH * LSEQ;

    __shared__ __align__(16) __bf16 sXt[64][40];   // [l][c]
    __shared__ __align__(16) __bf16 sW[256][40];   // [i][c]

    const int tid  = threadIdx.x;
    const int wv   = tid >> 6;
    const int lane = tid & 63;
    const int g    = lane >> 4;
    const int n16  = lane & 15;

    f32x4 acc[4][4];
    #pragma unroll
    for (int i = 0; i < 4; ++i)
        #pragma unroll
        for (int j = 0; j < 4; ++j)
            acc[i][j] = f32x4{0.f, 0.f, 0.f, 0.f};

    for (int kk = 0; kk < 8; ++kk) {
        const int c0 = kk * 32;
        __syncthreads();
        #pragma unroll
        for (int p = 0; p < 8; ++p) {
            const int i  = p * 32 + (tid >> 3);
            const int c4 = (tid & 7) * 4;
            const float4 v = *(const float4*)(W + (size_t)i * CH + c0 + c4);
            bf16x4 pk = { (__bf16)v.x, (__bf16)v.y, (__bf16)v.z, (__bf16)v.w };
            *(bf16x4*)&sW[i][c4] = pk;
        }
        #pragma unroll
        for (int p = 0; p < 2; ++p) {
            const int c  = p * 16 + (tid >> 4);
            const int l4 = (tid & 15) * 4;
            const float4 v = *(const float4*)(X + (size_t)(c0 + c) * LSEQ + l0 + l4);
            sXt[l4 + 0][c] = (__bf16)v.x;
            sXt[l4 + 1][c] = (__bf16)v.y;
            sXt[l4 + 2][c] = (__bf16)v.z;
            sXt[l4 + 3][c] = (__bf16)v.w;
        }
        __syncthreads();

        bf16x8 af[4], bfr[4];
        #pragma unroll
        for (int mr = 0; mr < 4; ++mr)
            af[mr] = *(const bf16x8*)&sXt[mr * 16 + n16][g * 8];
        #pragma unroll
        for (int nc = 0; nc < 4; ++nc)
            bfr[nc] = *(const bf16x8*)&sW[wv * 64 + nc * 16 + n16][g * 8];
        #pragma unroll
        for (int mr = 0; mr < 4; ++mr)
            #pragma unroll
            for (int nc = 0; nc < 4; ++nc)
                acc[mr][nc] = __builtin_amdgcn_mfma_f32_16x16x32_bf16(
                    af[mr], bfr[nc], acc[mr][nc], 0, 0, 0);
    }

    // D fragment: row l = mr*16 + g*4 + r, col i = nc*16 + n16 (+wv*64)
    if (which == 0) {
        __bf16* out = Q + (size_t)b * LSEQ * DIN;
        #pragma unroll
        for (int nc = 0; nc < 4; ++nc) {
            const int icol = wv * 64 + nc * 16 + n16;
            const float bb = bias[icol];
            #pragma unroll
            for (int mr = 0; mr < 4; ++mr) {
                const int lrow = l0 + mr * 16 + g * 4;
                #pragma unroll
                for (int r = 0; r < 4; ++r)
                    out[(size_t)(lrow + r) * DIN + icol] = (__bf16)(acc[mr][nc][r] + bb);
            }
        }
    } else if (which == 1) {
        #pragma unroll
        for (int nc = 0; nc < 4; ++nc) {
            const int icol = wv * 64 + nc * 16 + n16;
            const float bb = bias[icol];
            #pragma unroll
            for (int mr = 0; mr < 4; ++mr) {
                #pragma unroll
                for (int r = 0; r < 4; ++r) {
                    const int lrow = l0 + mr * 16 + g * 4 + r;
                    const int kt = lrow >> 6, row = lrow & 63;
                    const size_t off = ((size_t)(b * NT + kt) << 16)
                                     + (size_t)row * 512
                                     + ((icol * 2) ^ ((row & 7) << 4));
                    *(__bf16*)(KV + off) = (__bf16)(acc[mr][nc][r] + bb);
                }
            }
        }
    } else {
        #pragma unroll
        for (int nc = 0; nc < 4; ++nc) {
            const int d  = wv * 64 + nc * 16 + n16;
            const float bb = bias[d];
            #pragma unroll
            for (int mr = 0; mr < 4; ++mr) {
                const int lrow = l0 + mr * 16 + g * 4;   // 4 consecutive l, 8B run
                const int kt = lrow >> 6, c = lrow & 63;
                bf16x4 pk;
                #pragma unroll
                for (int r = 0; r < 4; ++r)
                    pk[r] = (__bf16)(acc[mr][nc][r] + bb);
                const size_t off = ((size_t)(b * NT + kt) << 16) + 32768
                                 + (size_t)d * 128
                                 + ((2 * c) ^ ((d & 7) << 4));
                *(bf16x4*)(KV + off) = pk;
            }
        }
    }
}

// ---------------------------------------------------------------------------
// Kernel 2: flash attention v3b.
// 512 threads = 8 waves = 2 groups x 4 waves. Q-tile 128: wave wq (=wv&3) owns
// rows wq*32..wq*32+31 (2 m-frags). Group grp (=wv>>2) processes kj half
// [grp*32, grp*32+32) of each 64-row KV tile with private online-softmax
// state; 2 waves/SIMD (one per group) hide each other's stalls.
// __launch_bounds__(512) (NO min-waves arg): R3's (512,2) capped VGPR at 128
// and spilled accO to scratch (+12MB WRITE_SIZE). 256-cap fits ~230 VGPR.
// End-of-kernel LDS merge combines the two groups' partial (m,l,accO).
// Double-buffered pre-swizzled KV tiles via global_load_lds + counted vmcnt.
// ---------------------------------------------------------------------------
__global__ __launch_bounds__(512) void attn_kernel(
    const __bf16* __restrict__ Q, const uint8_t* __restrict__ KV,
    __bf16* __restrict__ O)
{
    const int b   = blockIdx.x;
    const int q0  = blockIdx.y * 128;
    const int tid = threadIdx.x;
    const int wv  = tid >> 6, lane = tid & 63, g = lane >> 4, n16 = lane & 15;
    const int wq  = wv & 3, grp = wv >> 2;

    __shared__ __align__(1024) uint8_t sKV[2][65536];  // dbuf KV tile images
    __shared__ __align__(1024) uint8_t sP[16384];      // P [128 rows][128B] swizzled

    // Q fragments: 2 m-frags x 8 k-slices, rows q0 + wq*32 + m*16 + n16
    bf16x8 qf[2][8];
    #pragma unroll
    for (int m = 0; m < 2; ++m) {
        const __bf16* Qrow = Q + ((size_t)b * LSEQ + q0 + wq * 32 + m * 16 + n16) * DIN;
        #pragma unroll
        for (int ks = 0; ks < 8; ++ks)
            qf[m][ks] = *(const bf16x8*)(Qrow + ks * 32 + g * 8);
    }

    float m_i[2][4], l_i[2][4];
    #pragma unroll
    for (int m = 0; m < 2; ++m)
        #pragma unroll
        for (int r = 0; r < 4; ++r) { m_i[m][r] = -__builtin_inff(); l_i[m][r] = 0.f; }
    f32x4 accO[2][16];
    #pragma unroll
    for (int m = 0; m < 2; ++m)
        #pragma unroll
        for (int ds = 0; ds < 16; ++ds) accO[m][ds] = f32x4{0.f, 0.f, 0.f, 0.f};

    const uint8_t* KVb = KV + ((size_t)b * NT << 16);
    const float CEXP = 1.4426950408889634f / 16.0f;   // log2(e)/scale, scale=16

    // prologue: stage tile 0 (512 thr x 16B x 8 = 64KB)
    #pragma unroll
    for (int p = 0; p < 8; ++p) {
        const int off = p * 8192 + tid * 16;
        gload_lds16(KVb + off, &sKV[0][off]);
    }

    for (int t = 0; t < NT; ++t) {
        const int buf = t & 1;
        if (t + 1 < NT) {
            const uint8_t* src = KVb + ((size_t)(t + 1) << 16);
            #pragma unroll
            for (int p = 0; p < 8; ++p) {
                const int off = p * 8192 + tid * 16;
                gload_lds16(src + off, &sKV[buf ^ 1][off]);
            }
            asm volatile("s_waitcnt vmcnt(8)" ::: "memory");  // cur tile done, next in flight
        } else {
            asm volatile("s_waitcnt vmcnt(0)" ::: "memory");
        }
        __builtin_amdgcn_s_barrier();
        asm volatile("" ::: "memory");

        const uint8_t* kb = sKV[buf];

        // ---- QK^T on this group's kj half: D[qi][kj], 2 m share each K frag ----
        f32x4 sacc[2][2];
        #pragma unroll
        for (int m = 0; m < 2; ++m)
            #pragma unroll
            for (int nc = 0; nc < 2; ++nc) sacc[m][nc] = f32x4{0.f, 0.f, 0.f, 0.f};
        #pragma unroll
        for (int ks = 0; ks < 8; ++ks) {
            #pragma unroll
            for (int nc = 0; nc < 2; ++nc) {
                const int row = grp * 32 + nc * 16 + n16;
                const bf16x8 kf = *(const bf16x8*)(kb + row * 512
                                   + ((ks * 64 + g * 16) ^ ((row & 7) << 4)));
                sacc[0][nc] = __builtin_amdgcn_mfma_f32_16x16x32_bf16(qf[0][ks], kf, sacc[0][nc], 0, 0, 0);
                sacc[1][nc] = __builtin_amdgcn_mfma_f32_16x16x32_bf16(qf[1][ks], kf, sacc[1][nc], 0, 0, 0);
            }
        }

        // ---- online softmax (group-private; lane rows g*4+r) ----
        #pragma unroll
        for (int m = 0; m < 2; ++m) {
            float scl[4];
            #pragma unroll
            for (int r = 0; r < 4; ++r) {
                float rmax = fmaxf(sacc[m][0][r], sacc[m][1][r]);
                rmax = fmaxf(rmax, __shfl_xor(rmax, 1));
                rmax = fmaxf(rmax, __shfl_xor(rmax, 2));
                rmax = fmaxf(rmax, __shfl_xor(rmax, 4));
                rmax = fmaxf(rmax, __shfl_xor(rmax, 8));
                const float mnew = fmaxf(m_i[m][r], rmax);
                scl[r] = exp2f((m_i[m][r] - mnew) * CEXP);
                float pv0 = exp2f((sacc[m][0][r] - mnew) * CEXP);
                float pv1 = exp2f((sacc[m][1][r] - mnew) * CEXP);
                sacc[m][0][r] = pv0;
                sacc[m][1][r] = pv1;
                float rsum = pv0 + pv1;
                rsum += __shfl_xor(rsum, 1);
                rsum += __shfl_xor(rsum, 2);
                rsum += __shfl_xor(rsum, 4);
                rsum += __shfl_xor(rsum, 8);
                l_i[m][r] = l_i[m][r] * scl[r] + rsum;
                m_i[m][r] = mnew;
            }
            #pragma unroll
            for (int ds = 0; ds < 16; ++ds)
                #pragma unroll
                for (int r = 0; r < 4; ++r)
                    accO[m][ds][r] *= scl[r];
            // P -> LDS (wave-private rows+cols, swizzled; DS in-order per wave)
            #pragma unroll
            for (int r = 0; r < 4; ++r) {
                const int row = wq * 32 + m * 16 + g * 4 + r;
                #pragma unroll
                for (int nc = 0; nc < 2; ++nc) {
                    const int cb = 2 * (grp * 32 + nc * 16 + n16);
                    *(__bf16*)(sP + row * 128 + (cb ^ ((row & 7) << 4))) =
                        (__bf16)sacc[m][nc][r];
                }
            }
        }

        // ---- PV on this group's kj half ----
        bf16x8 af[2];
        #pragma unroll
        for (int m = 0; m < 2; ++m) {
            const int row = wq * 32 + m * 16 + n16;
            af[m] = *(const bf16x8*)(sP + row * 128
                      + ((grp * 64 + g * 16) ^ ((row & 7) << 4)));
        }
        #pragma unroll
        for (int ds = 0; ds < 16; ++ds) {
            const int d = ds * 16 + n16;
            const bf16x8 vf = *(const bf16x8*)(kb + 32768 + d * 128
                               + ((grp * 64 + g * 16) ^ ((d & 7) << 4)));
            accO[0][ds] = __builtin_amdgcn_mfma_f32_16x16x32_bf16(af[0], vf, accO[0][ds], 0, 0, 0);
            accO[1][ds] = __builtin_amdgcn_mfma_f32_16x16x32_bf16(af[1], vf, accO[1][ds], 0, 0, 0);
        }

        asm volatile("" ::: "memory");
        __builtin_amdgcn_s_barrier();   // all waves done reading buf before overwrite
    }

    // ---- cross-group merge: group 1 publishes (accO, m, l); group 0 combines ----
    float* shA = (float*)sKV;   // 32768 f32 = 128KB: [wq][slot 0..31][lane][r]
    float* shM = (float*)sP;    // 4096 f32: [wq][slot 0..15][lane]
    if (grp == 1) {
        #pragma unroll
        for (int m = 0; m < 2; ++m)
            #pragma unroll
            for (int ds = 0; ds < 16; ++ds)
                *(f32x4*)&shA[wq * 8192 + (m * 16 + ds) * 256 + lane * 4] = accO[m][ds];
        #pragma unroll
        for (int m = 0; m < 2; ++m)
            #pragma unroll
            for (int r = 0; r < 4; ++r) {
                shM[wq * 1024 + (m * 4 + r) * 64 + lane]       = m_i[m][r];
                shM[wq * 1024 + 512 + (m * 4 + r) * 64 + lane] = l_i[m][r];
            }
    }
    __syncthreads();
    if (grp == 0) {
        #pragma unroll
        for (int m = 0; m < 2; ++m) {
            float s0[4], s1[4];
            #pragma unroll
            for (int r = 0; r < 4; ++r) {
                const float m1 = shM[wq * 1024 + (m * 4 + r) * 64 + lane];
                const float l1 = shM[wq * 1024 + 512 + (m * 4 + r) * 64 + lane];
                const float mM = fmaxf(m_i[m][r], m1);
                const float e0 = exp2f((m_i[m][r] - mM) * CEXP);
                const float e1 = exp2f((m1 - mM) * CEXP);
                const float dinv = 1.f / (l_i[m][r] * e0 + l1 * e1);
                s0[r] = e0 * dinv;
                s1[r] = e1 * dinv;
            }
            __bf16* Ob = O + ((size_t)b * LSEQ + q0 + wq * 32 + m * 16) * DIN;
            #pragma unroll
            for (int ds = 0; ds < 16; ++ds) {
                const f32x4 a1 = *(const f32x4*)&shA[wq * 8192 + (m * 16 + ds) * 256 + lane * 4];
                #pragma unroll
                for (int r = 0; r < 4; ++r)
                    Ob[(size_t)(g * 4 + r) * DIN + ds * 16 + n16] =
                        (__bf16)(accO[m][ds][r] * s0[r] + a1[r] * s1[r]);
            }
        }
    }
}

// ---------------------------------------------------------------------------
// Kernel 3: output projection. out[b][c][l] = sum_i Wo[c][i]*O[b][l][i] + bo[c].
// ---------------------------------------------------------------------------
__global__ __launch_bounds__(256) void out_proj_kernel(
    const float* __restrict__ Wo, const float* __restrict__ bo,
    const __bf16* __restrict__ O, float* __restrict__ out)
{
    const int b   = blockIdx.z;
    const int c0  = blockIdx.y * 64;
    const int l0  = blockIdx.x * 256;
    const int tid = threadIdx.x;
    const int wv  = tid >> 6, lane = tid & 63, g = lane >> 4, n16 = lane & 15;

    __shared__ __align__(16) __bf16 sWo[64][40];   // [c][i]
    __shared__ __align__(16) __bf16 sO[256][40];   // [l][i]

    const __bf16* Ob = O + (size_t)b * LSEQ * DIN;

    f32x4 acc[4][4];
    #pragma unroll
    for (int i = 0; i < 4; ++i)
        #pragma unroll
        for (int j = 0; j < 4; ++j)
            acc[i][j] = f32x4{0.f, 0.f, 0.f, 0.f};

    for (int kk = 0; kk < 8; ++kk) {
        const int i0 = kk * 32;
        __syncthreads();
        #pragma unroll
        for (int p = 0; p < 2; ++p) {
            const int c  = p * 32 + (tid >> 3);
            const int i4 = (tid & 7) * 4;
            const float4 v = *(const float4*)(Wo + (size_t)(c0 + c) * DIN + i0 + i4);
            bf16x4 pk = { (__bf16)v.x, (__bf16)v.y, (__bf16)v.z, (__bf16)v.w };
            *(bf16x4*)&sWo[c][i4] = pk;
        }
        #pragma unroll
        for (int p = 0; p < 4; ++p) {
            const int l  = p * 64 + (tid >> 2);
            const int sg = tid & 3;
            *(uint4*)&sO[l][sg * 8] = *(const uint4*)(Ob + (size_t)(l0 + l) * DIN + i0 + sg * 8);
        }
        __syncthreads();

        bf16x8 af[4], bfr[4];
        #pragma unroll
        for (int mr = 0; mr < 4; ++mr)
            af[mr] = *(const bf16x8*)&sWo[mr * 16 + n16][g * 8];
        #pragma unroll
        for (int nc = 0; nc < 4; ++nc)
            bfr[nc] = *(const bf16x8*)&sO[wv * 64 + nc * 16 + n16][g * 8];
        #pragma unroll
        for (int mr = 0; mr < 4; ++mr)
            #pragma unroll
            for (int nc = 0; nc < 4; ++nc)
                acc[mr][nc] = __builtin_amdgcn_mfma_f32_16x16x32_bf16(
                    af[mr], bfr[nc], acc[mr][nc], 0, 0, 0);
    }

    #pragma unroll
    for (int mr = 0; mr < 4; ++mr) {
        const int c = c0 + mr * 16 + g * 4;
        #pragma unroll
        for (int nc = 0; nc < 4; ++nc) {
            const int l = l0 + wv * 64 + nc * 16 + n16;
            #pragma unroll
            for (int r = 0; r < 4; ++r)
                out[((size_t)b * CH + c + r) * LSEQ + l] = acc[mr][nc][r] + bo[c + r];
        }
    }
}

// ---------------------------------------------------------------------------
extern "C" void kernel_launch(void* const* d_in, const int* in_sizes, int n_in,
                              void* d_out, int out_size, void* d_ws, size_t ws_size,
                              hipStream_t stream)
{
    const float* x  = (const float*)d_in[0];
    const float* Wq = (const float*)d_in[1];
    const float* bq = (const float*)d_in[2];
    const float* Wk = (const float*)d_in[3];
    const float* bk = (const float*)d_in[4];
    const float* Wv = (const float*)d_in[5];
    const float* bv = (const float*)d_in[6];
    const float* Wo = (const float*)d_in[7];
    const float* bo = (const float*)d_in[8];
    float* out = (float*)d_out;

    // ws: Q bf16 16MB | KV swizzled tile images 32MB | O bf16 16MB = 64MB
    __bf16*  Q  = (__bf16*)d_ws;
    uint8_t* KV = (uint8_t*)d_ws + (16u << 20);
    __bf16*  O  = (__bf16*)((uint8_t*)d_ws + (48u << 20));

    qkv_proj_kernel<<<dim3(LSEQ / 64, 3, BS), 256, 0, stream>>>(
        x, Wq, bq, Wk, bk, Wv, bv, Q, KV);
    attn_kernel<<<dim3(BS, LSEQ / 128), 512, 0, stream>>>(Q, KV, O);
    out_proj_kernel<<<dim3(LSEQ / 256, CH / 64, BS), 256, 0, stream>>>(Wo, bo, O, out);
}

// Round 5
// 448.270 us; speedup vs baseline: 1.0006x; 1.0006x over previous
//
#include <hip/hip_runtime.h>
#include <stdint.h>

#define BS   8
#define CH   256    // C
#define LSEQ 4096   // H*W
#define DIN  256    // INNER
#define NT   64     // number of KV tiles
#define KT   64     // kv rows per tile

typedef __bf16 bf16x8 __attribute__((ext_vector_type(8)));
typedef __bf16 bf16x4 __attribute__((ext_vector_type(4)));
typedef float  f32x4  __attribute__((ext_vector_type(4)));

// async global->LDS, 16B per lane; LDS dest = wave-uniform base + lane*16
__device__ __forceinline__ void gload_lds16(const void* g, void* l) {
    __builtin_amdgcn_global_load_lds(
        (const __attribute__((address_space(1))) uint32_t*)g,
        (__attribute__((address_space(3))) uint32_t*)l, 16, 0, 0);
}

// ---------------------------------------------------------------------------
// Kernel 1: QKV projection. Y[l][i] = sum_c X[c][l]*W[i][c] + b[i].
// which==0 -> Q linear [l][i] bf16.
// which==1 -> K into swizzled tile image: tile(b,kt) 32KB, byte =
//             row*512 + ((2i) ^ ((row&7)<<4)), row = l&63.
// which==2 -> V into tile image second half: byte = 32768 + d*128 +
//             ((2*(l&63)) ^ ((d&7)<<4)).
// KV tile = 64KB: [K img 32KB][V img 32KB], contiguous per (b,kt).
// ---------------------------------------------------------------------------
__global__ __launch_bounds__(256) void qkv_proj_kernel(
    const float* __restrict__ x,
    const float* __restrict__ Wq, const float* __restrict__ bq,
    const float* __restrict__ Wk, const float* __restrict__ bk,
    const float* __restrict__ Wv, const float* __restrict__ bv,
    __bf16* __restrict__ Q, uint8_t* __restrict__ KV)
{
    const int b     = blockIdx.z;
    const int which = blockIdx.y;
    const int l0    = blockIdx.x * 64;

    const float* W    = (which == 0) ? Wq : (which == 1) ? Wk : Wv;
    const float* bias = (which == 0) ? bq : (which == 1) ? bk : bv;
    const float* X    = x + (size_t)b * CH * LSEQ;

    __shared__ __align__(16) __bf16 sXt[64][40];   // [l][c]
    __shared__ __align__(16) __bf16 sW[256][40];   // [i][c]

    const int tid  = threadIdx.x;
    const int wv   = tid >> 6;
    const int lane = tid & 63;
    const int g    = lane >> 4;
    const int n16  = lane & 15;

    f32x4 acc[4][4];
    #pragma unroll
    for (int i = 0; i < 4; ++i)
        #pragma unroll
        for (int j = 0; j < 4; ++j)
            acc[i][j] = f32x4{0.f, 0.f, 0.f, 0.f};

    for (int kk = 0; kk < 8; ++kk) {
        const int c0 = kk * 32;
        __syncthreads();
        #pragma unroll
        for (int p = 0; p < 8; ++p) {
            const int i  = p * 32 + (tid >> 3);
            const int c4 = (tid & 7) * 4;
            const float4 v = *(const float4*)(W + (size_t)i * CH + c0 + c4);
            bf16x4 pk = { (__bf16)v.x, (__bf16)v.y, (__bf16)v.z, (__bf16)v.w };
            *(bf16x4*)&sW[i][c4] = pk;
        }
        #pragma unroll
        for (int p = 0; p < 2; ++p) {
            const int c  = p * 16 + (tid >> 4);
            const int l4 = (tid & 15) * 4;
            const float4 v = *(const float4*)(X + (size_t)(c0 + c) * LSEQ + l0 + l4);
            sXt[l4 + 0][c] = (__bf16)v.x;
            sXt[l4 + 1][c] = (__bf16)v.y;
            sXt[l4 + 2][c] = (__bf16)v.z;
            sXt[l4 + 3][c] = (__bf16)v.w;
        }
        __syncthreads();

        bf16x8 af[4], bfr[4];
        #pragma unroll
        for (int mr = 0; mr < 4; ++mr)
            af[mr] = *(const bf16x8*)&sXt[mr * 16 + n16][g * 8];
        #pragma unroll
        for (int nc = 0; nc < 4; ++nc)
            bfr[nc] = *(const bf16x8*)&sW[wv * 64 + nc * 16 + n16][g * 8];
        #pragma unroll
        for (int mr = 0; mr < 4; ++mr)
            #pragma unroll
            for (int nc = 0; nc < 4; ++nc)
                acc[mr][nc] = __builtin_amdgcn_mfma_f32_16x16x32_bf16(
                    af[mr], bfr[nc], acc[mr][nc], 0, 0, 0);
    }

    // D fragment: row l = mr*16 + g*4 + r, col i = nc*16 + n16 (+wv*64)
    if (which == 0) {
        __bf16* out = Q + (size_t)b * LSEQ * DIN;
        #pragma unroll
        for (int nc = 0; nc < 4; ++nc) {
            const int icol = wv * 64 + nc * 16 + n16;
            const float bb = bias[icol];
            #pragma unroll
            for (int mr = 0; mr < 4; ++mr) {
                const int lrow = l0 + mr * 16 + g * 4;
                #pragma unroll
                for (int r = 0; r < 4; ++r)
                    out[(size_t)(lrow + r) * DIN + icol] = (__bf16)(acc[mr][nc][r] + bb);
            }
        }
    } else if (which == 1) {
        #pragma unroll
        for (int nc = 0; nc < 4; ++nc) {
            const int icol = wv * 64 + nc * 16 + n16;
            const float bb = bias[icol];
            #pragma unroll
            for (int mr = 0; mr < 4; ++mr) {
                #pragma unroll
                for (int r = 0; r < 4; ++r) {
                    const int lrow = l0 + mr * 16 + g * 4 + r;
                    const int kt = lrow >> 6, row = lrow & 63;
                    const size_t off = ((size_t)(b * NT + kt) << 16)
                                     + (size_t)row * 512
                                     + ((icol * 2) ^ ((row & 7) << 4));
                    *(__bf16*)(KV + off) = (__bf16)(acc[mr][nc][r] + bb);
                }
            }
        }
    } else {
        #pragma unroll
        for (int nc = 0; nc < 4; ++nc) {
            const int d  = wv * 64 + nc * 16 + n16;
            const float bb = bias[d];
            #pragma unroll
            for (int mr = 0; mr < 4; ++mr) {
                const int lrow = l0 + mr * 16 + g * 4;   // 4 consecutive l, 8B run
                const int kt = lrow >> 6, c = lrow & 63;
                bf16x4 pk;
                #pragma unroll
                for (int r = 0; r < 4; ++r)
                    pk[r] = (__bf16)(acc[mr][nc][r] + bb);
                const size_t off = ((size_t)(b * NT + kt) << 16) + 32768
                                 + (size_t)d * 128
                                 + ((2 * c) ^ ((d & 7) << 4));
                *(bf16x4*)(KV + off) = pk;
            }
        }
    }
}

// ---------------------------------------------------------------------------
// Kernel 2: flash attention v3c.
// 512 threads = 8 waves = 2 groups x 4 waves. Q-tile 128: wave wq (=wv&3) owns
// rows wq*32..wq*32+31 (2 m-frags). Group grp (=wv>>2) processes kj half
// [grp*32, grp*32+32) of each 64-row KV tile with private online-softmax
// state; 2 waves/SIMD (one per group) hide each other's stalls.
// amdgpu_waves_per_eu(2,2): R3/R4 showed the compiler's default heuristic for
// 512-thread workgroups picks a 128-VGPR budget (4 waves/EU target) and spills
// ~100 regs (+12MB scratch WRITE_SIZE). LDS (144KB) caps us at 1 block/CU =
// 2 waves/EU regardless, so pin the budget at 512/2 = 256 regs/wave.
// End-of-kernel LDS merge combines the two groups' partial (m,l,accO).
// Double-buffered pre-swizzled KV tiles via global_load_lds + counted vmcnt.
// ---------------------------------------------------------------------------
__global__ __launch_bounds__(512)
__attribute__((amdgpu_waves_per_eu(2, 2)))
void attn_kernel(
    const __bf16* __restrict__ Q, const uint8_t* __restrict__ KV,
    __bf16* __restrict__ O)
{
    const int b   = blockIdx.x;
    const int q0  = blockIdx.y * 128;
    const int tid = threadIdx.x;
    const int wv  = tid >> 6, lane = tid & 63, g = lane >> 4, n16 = lane & 15;
    const int wq  = wv & 3, grp = wv >> 2;

    __shared__ __align__(1024) uint8_t sKV[2][65536];  // dbuf KV tile images
    __shared__ __align__(1024) uint8_t sP[16384];      // P [128 rows][128B] swizzled

    // Q fragments: 2 m-frags x 8 k-slices, rows q0 + wq*32 + m*16 + n16
    bf16x8 qf[2][8];
    #pragma unroll
    for (int m = 0; m < 2; ++m) {
        const __bf16* Qrow = Q + ((size_t)b * LSEQ + q0 + wq * 32 + m * 16 + n16) * DIN;
        #pragma unroll
        for (int ks = 0; ks < 8; ++ks)
            qf[m][ks] = *(const bf16x8*)(Qrow + ks * 32 + g * 8);
    }

    float m_i[2][4], l_i[2][4];
    #pragma unroll
    for (int m = 0; m < 2; ++m)
        #pragma unroll
        for (int r = 0; r < 4; ++r) { m_i[m][r] = -__builtin_inff(); l_i[m][r] = 0.f; }
    f32x4 accO[2][16];
    #pragma unroll
    for (int m = 0; m < 2; ++m)
        #pragma unroll
        for (int ds = 0; ds < 16; ++ds) accO[m][ds] = f32x4{0.f, 0.f, 0.f, 0.f};

    const uint8_t* KVb = KV + ((size_t)b * NT << 16);
    const float CEXP = 1.4426950408889634f / 16.0f;   // log2(e)/scale, scale=16

    // prologue: stage tile 0 (512 thr x 16B x 8 = 64KB)
    #pragma unroll
    for (int p = 0; p < 8; ++p) {
        const int off = p * 8192 + tid * 16;
        gload_lds16(KVb + off, &sKV[0][off]);
    }

    for (int t = 0; t < NT; ++t) {
        const int buf = t & 1;
        if (t + 1 < NT) {
            const uint8_t* src = KVb + ((size_t)(t + 1) << 16);
            #pragma unroll
            for (int p = 0; p < 8; ++p) {
                const int off = p * 8192 + tid * 16;
                gload_lds16(src + off, &sKV[buf ^ 1][off]);
            }
            asm volatile("s_waitcnt vmcnt(8)" ::: "memory");  // cur tile done, next in flight
        } else {
            asm volatile("s_waitcnt vmcnt(0)" ::: "memory");
        }
        __builtin_amdgcn_s_barrier();
        asm volatile("" ::: "memory");

        const uint8_t* kb = sKV[buf];

        // ---- QK^T on this group's kj half: D[qi][kj], 2 m share each K frag ----
        f32x4 sacc[2][2];
        #pragma unroll
        for (int m = 0; m < 2; ++m)
            #pragma unroll
            for (int nc = 0; nc < 2; ++nc) sacc[m][nc] = f32x4{0.f, 0.f, 0.f, 0.f};
        #pragma unroll
        for (int ks = 0; ks < 8; ++ks) {
            #pragma unroll
            for (int nc = 0; nc < 2; ++nc) {
                const int row = grp * 32 + nc * 16 + n16;
                const bf16x8 kf = *(const bf16x8*)(kb + row * 512
                                   + ((ks * 64 + g * 16) ^ ((row & 7) << 4)));
                sacc[0][nc] = __builtin_amdgcn_mfma_f32_16x16x32_bf16(qf[0][ks], kf, sacc[0][nc], 0, 0, 0);
                sacc[1][nc] = __builtin_amdgcn_mfma_f32_16x16x32_bf16(qf[1][ks], kf, sacc[1][nc], 0, 0, 0);
            }
        }

        // ---- online softmax (group-private; lane rows g*4+r) ----
        #pragma unroll
        for (int m = 0; m < 2; ++m) {
            float scl[4];
            #pragma unroll
            for (int r = 0; r < 4; ++r) {
                float rmax = fmaxf(sacc[m][0][r], sacc[m][1][r]);
                rmax = fmaxf(rmax, __shfl_xor(rmax, 1));
                rmax = fmaxf(rmax, __shfl_xor(rmax, 2));
                rmax = fmaxf(rmax, __shfl_xor(rmax, 4));
                rmax = fmaxf(rmax, __shfl_xor(rmax, 8));
                const float mnew = fmaxf(m_i[m][r], rmax);
                scl[r] = exp2f((m_i[m][r] - mnew) * CEXP);
                float pv0 = exp2f((sacc[m][0][r] - mnew) * CEXP);
                float pv1 = exp2f((sacc[m][1][r] - mnew) * CEXP);
                sacc[m][0][r] = pv0;
                sacc[m][1][r] = pv1;
                float rsum = pv0 + pv1;
                rsum += __shfl_xor(rsum, 1);
                rsum += __shfl_xor(rsum, 2);
                rsum += __shfl_xor(rsum, 4);
                rsum += __shfl_xor(rsum, 8);
                l_i[m][r] = l_i[m][r] * scl[r] + rsum;
                m_i[m][r] = mnew;
            }
            #pragma unroll
            for (int ds = 0; ds < 16; ++ds)
                #pragma unroll
                for (int r = 0; r < 4; ++r)
                    accO[m][ds][r] *= scl[r];
            // P -> LDS (wave-private rows+cols, swizzled; DS in-order per wave)
            #pragma unroll
            for (int r = 0; r < 4; ++r) {
                const int row = wq * 32 + m * 16 + g * 4 + r;
                #pragma unroll
                for (int nc = 0; nc < 2; ++nc) {
                    const int cb = 2 * (grp * 32 + nc * 16 + n16);
                    *(__bf16*)(sP + row * 128 + (cb ^ ((row & 7) << 4))) =
                        (__bf16)sacc[m][nc][r];
                }
            }
        }

        // ---- PV on this group's kj half ----
        bf16x8 af[2];
        #pragma unroll
        for (int m = 0; m < 2; ++m) {
            const int row = wq * 32 + m * 16 + n16;
            af[m] = *(const bf16x8*)(sP + row * 128
                      + ((grp * 64 + g * 16) ^ ((row & 7) << 4)));
        }
        #pragma unroll
        for (int ds = 0; ds < 16; ++ds) {
            const int d = ds * 16 + n16;
            const bf16x8 vf = *(const bf16x8*)(kb + 32768 + d * 128
                               + ((grp * 64 + g * 16) ^ ((d & 7) << 4)));
            accO[0][ds] = __builtin_amdgcn_mfma_f32_16x16x32_bf16(af[0], vf, accO[0][ds], 0, 0, 0);
            accO[1][ds] = __builtin_amdgcn_mfma_f32_16x16x32_bf16(af[1], vf, accO[1][ds], 0, 0, 0);
        }

        asm volatile("" ::: "memory");
        __builtin_amdgcn_s_barrier();   // all waves done reading buf before overwrite
    }

    // ---- cross-group merge: group 1 publishes (accO, m, l); group 0 combines ----
    float* shA = (float*)sKV;   // 32768 f32 = 128KB: [wq][slot 0..31][lane][r]
    float* shM = (float*)sP;    // 4096 f32: [wq][slot 0..15][lane]
    if (grp == 1) {
        #pragma unroll
        for (int m = 0; m < 2; ++m)
            #pragma unroll
            for (int ds = 0; ds < 16; ++ds)
                *(f32x4*)&shA[wq * 8192 + (m * 16 + ds) * 256 + lane * 4] = accO[m][ds];
        #pragma unroll
        for (int m = 0; m < 2; ++m)
            #pragma unroll
            for (int r = 0; r < 4; ++r) {
                shM[wq * 1024 + (m * 4 + r) * 64 + lane]       = m_i[m][r];
                shM[wq * 1024 + 512 + (m * 4 + r) * 64 + lane] = l_i[m][r];
            }
    }
    __syncthreads();
    if (grp == 0) {
        #pragma unroll
        for (int m = 0; m < 2; ++m) {
            float s0[4], s1[4];
            #pragma unroll
            for (int r = 0; r < 4; ++r) {
                const float m1 = shM[wq * 1024 + (m * 4 + r) * 64 + lane];
                const float l1 = shM[wq * 1024 + 512 + (m * 4 + r) * 64 + lane];
                const float mM = fmaxf(m_i[m][r], m1);
                const float e0 = exp2f((m_i[m][r] - mM) * CEXP);
                const float e1 = exp2f((m1 - mM) * CEXP);
                const float dinv = 1.f / (l_i[m][r] * e0 + l1 * e1);
                s0[r] = e0 * dinv;
                s1[r] = e1 * dinv;
            }
            __bf16* Ob = O + ((size_t)b * LSEQ + q0 + wq * 32 + m * 16) * DIN;
            #pragma unroll
            for (int ds = 0; ds < 16; ++ds) {
                const f32x4 a1 = *(const f32x4*)&shA[wq * 8192 + (m * 16 + ds) * 256 + lane * 4];
                #pragma unroll
                for (int r = 0; r < 4; ++r)
                    Ob[(size_t)(g * 4 + r) * DIN + ds * 16 + n16] =
                        (__bf16)(accO[m][ds][r] * s0[r] + a1[r] * s1[r]);
            }
        }
    }
}

// ---------------------------------------------------------------------------
// Kernel 3: output projection. out[b][c][l] = sum_i Wo[c][i]*O[b][l][i] + bo[c].
// ---------------------------------------------------------------------------
__global__ __launch_bounds__(256) void out_proj_kernel(
    const float* __restrict__ Wo, const float* __restrict__ bo,
    const __bf16* __restrict__ O, float* __restrict__ out)
{
    const int b   = blockIdx.z;
    const int c0  = blockIdx.y * 64;
    const int l0  = blockIdx.x * 256;
    const int tid = threadIdx.x;
    const int wv  = tid >> 6, lane = tid & 63, g = lane >> 4, n16 = lane & 15;

    __shared__ __align__(16) __bf16 sWo[64][40];   // [c][i]
    __shared__ __align__(16) __bf16 sO[256][40];   // [l][i]

    const __bf16* Ob = O + (size_t)b * LSEQ * DIN;

    f32x4 acc[4][4];
    #pragma unroll
    for (int i = 0; i < 4; ++i)
        #pragma unroll
        for (int j = 0; j < 4; ++j)
            acc[i][j] = f32x4{0.f, 0.f, 0.f, 0.f};

    for (int kk = 0; kk < 8; ++kk) {
        const int i0 = kk * 32;
        __syncthreads();
        #pragma unroll
        for (int p = 0; p < 2; ++p) {
            const int c  = p * 32 + (tid >> 3);
            const int i4 = (tid & 7) * 4;
            const float4 v = *(const float4*)(Wo + (size_t)(c0 + c) * DIN + i0 + i4);
            bf16x4 pk = { (__bf16)v.x, (__bf16)v.y, (__bf16)v.z, (__bf16)v.w };
            *(bf16x4*)&sWo[c][i4] = pk;
        }
        #pragma unroll
        for (int p = 0; p < 4; ++p) {
            const int l  = p * 64 + (tid >> 2);
            const int sg = tid & 3;
            *(uint4*)&sO[l][sg * 8] = *(const uint4*)(Ob + (size_t)(l0 + l) * DIN + i0 + sg * 8);
        }
        __syncthreads();

        bf16x8 af[4], bfr[4];
        #pragma unroll
        for (int mr = 0; mr < 4; ++mr)
            af[mr] = *(const bf16x8*)&sWo[mr * 16 + n16][g * 8];
        #pragma unroll
        for (int nc = 0; nc < 4; ++nc)
            bfr[nc] = *(const bf16x8*)&sO[wv * 64 + nc * 16 + n16][g * 8];
        #pragma unroll
        for (int mr = 0; mr < 4; ++mr)
            #pragma unroll
            for (int nc = 0; nc < 4; ++nc)
                acc[mr][nc] = __builtin_amdgcn_mfma_f32_16x16x32_bf16(
                    af[mr], bfr[nc], acc[mr][nc], 0, 0, 0);
    }

    #pragma unroll
    for (int mr = 0; mr < 4; ++mr) {
        const int c = c0 + mr * 16 + g * 4;
        #pragma unroll
        for (int nc = 0; nc < 4; ++nc) {
            const int l = l0 + wv * 64 + nc * 16 + n16;
            #pragma unroll
            for (int r = 0; r < 4; ++r)
                out[((size_t)b * CH + c + r) * LSEQ + l] = acc[mr][nc][r] + bo[c + r];
        }
    }
}

// ---------------------------------------------------------------------------
extern "C" void kernel_launch(void* const* d_in, const int* in_sizes, int n_in,
                              void* d_out, int out_size, void* d_ws, size_t ws_size,
                              hipStream_t stream)
{
    const float* x  = (const float*)d_in[0];
    const float* Wq = (const float*)d_in[1];
    const float* bq = (const float*)d_in[2];
    const float* Wk = (const float*)d_in[3];
    const float* bk = (const float*)d_in[4];
    const float* Wv = (const float*)d_in[5];
    const float* bv = (const float*)d_in[6];
    const float* Wo = (const float*)d_in[7];
    const float* bo = (const float*)d_in[8];
    float* out = (float*)d_out;

    // ws: Q bf16 16MB | KV swizzled tile images 32MB | O bf16 16MB = 64MB
    __bf16*  Q  = (__bf16*)d_ws;
    uint8_t* KV = (uint8_t*)d_ws + (16u << 20);
    __bf16*  O  = (__bf16*)((uint8_t*)d_ws + (48u << 20));

    qkv_proj_kernel<<<dim3(LSEQ / 64, 3, BS), 256, 0, stream>>>(
        x, Wq, bq, Wk, bk, Wv, bv, Q, KV);
    attn_kernel<<<dim3(BS, LSEQ / 128), 512, 0, stream>>>(Q, KV, O);
    out_proj_kernel<<<dim3(LSEQ / 256, CH / 64, BS), 256, 0, stream>>>(Wo, bo, O, out);
}

// Round 6
// 341.998 us; speedup vs baseline: 1.3115x; 1.3107x over previous
//
#include <hip/hip_runtime.h>
#include <stdint.h>

#define BS   8
#define CH   256    // C
#define LSEQ 4096   // H*W
#define DIN  256    // INNER
#define NT2  128    // number of KV tiles (32 rows each)
#define KT2  32     // kv rows per tile

typedef __bf16 bf16x8 __attribute__((ext_vector_type(8)));
typedef __bf16 bf16x4 __attribute__((ext_vector_type(4)));
typedef float  f32x4  __attribute__((ext_vector_type(4)));

// async global->LDS, 16B per lane; LDS dest = wave-uniform base + lane*16
__device__ __forceinline__ void gload_lds16(const void* g, void* l) {
    __builtin_amdgcn_global_load_lds(
        (const __attribute__((address_space(1))) uint32_t*)g,
        (__attribute__((address_space(3))) uint32_t*)l, 16, 0, 0);
}

// ---------------------------------------------------------------------------
// Kernel 1: QKV projection. Y[l][i] = sum_c X[c][l]*W[i][c] + b[i].
// which==0 -> Q linear [l][i] bf16.
// which==1 -> K into swizzled tile image: tile(b,t2) 32KB, K half 16KB:
//             byte = row*512 + ((2i) ^ ((row&7)<<4)), row = l&31.
// which==2 -> V half at +16384: d-pair rows of 128B:
//             byte = 16384 + (d>>1)*128 + (((d&1)*64 + 2*(l&31)) ^ (((d>>1)&7)<<4)).
// Tile stride 32KB; base = (b*128 + t2) << 15.
// ---------------------------------------------------------------------------
__global__ __launch_bounds__(256) void qkv_proj_kernel(
    const float* __restrict__ x,
    const float* __restrict__ Wq, const float* __restrict__ bq,
    const float* __restrict__ Wk, const float* __restrict__ bk,
    const float* __restrict__ Wv, const float* __restrict__ bv,
    __bf16* __restrict__ Q, uint8_t* __restrict__ KV)
{
    const int b     = blockIdx.z;
    const int which = blockIdx.y;
    const int l0    = blockIdx.x * 64;

    const float* W    = (which == 0) ? Wq : (which == 1) ? Wk : Wv;
    const float* bias = (which == 0) ? bq : (which == 1) ? bk : bv;
    const float* X    = x + (size_t)b * CH * LSEQ;

    __shared__ __align__(16) __bf16 sXt[64][40];   // [l][c]
    __shared__ __align__(16) __bf16 sW[256][40];   // [i][c]

    const int tid  = threadIdx.x;
    const int wv   = tid >> 6;
    const int lane = tid & 63;
    const int g    = lane >> 4;
    const int n16  = lane & 15;

    f32x4 acc[4][4];
    #pragma unroll
    for (int i = 0; i < 4; ++i)
        #pragma unroll
        for (int j = 0; j < 4; ++j)
            acc[i][j] = f32x4{0.f, 0.f, 0.f, 0.f};

    for (int kk = 0; kk < 8; ++kk) {
        const int c0 = kk * 32;
        __syncthreads();
        #pragma unroll
        for (int p = 0; p < 8; ++p) {
            const int i  = p * 32 + (tid >> 3);
            const int c4 = (tid & 7) * 4;
            const float4 v = *(const float4*)(W + (size_t)i * CH + c0 + c4);
            bf16x4 pk = { (__bf16)v.x, (__bf16)v.y, (__bf16)v.z, (__bf16)v.w };
            *(bf16x4*)&sW[i][c4] = pk;
        }
        #pragma unroll
        for (int p = 0; p < 2; ++p) {
            const int c  = p * 16 + (tid >> 4);
            const int l4 = (tid & 15) * 4;
            const float4 v = *(const float4*)(X + (size_t)(c0 + c) * LSEQ + l0 + l4);
            sXt[l4 + 0][c] = (__bf16)v.x;
            sXt[l4 + 1][c] = (__bf16)v.y;
            sXt[l4 + 2][c] = (__bf16)v.z;
            sXt[l4 + 3][c] = (__bf16)v.w;
        }
        __syncthreads();

        bf16x8 af[4], bfr[4];
        #pragma unroll
        for (int mr = 0; mr < 4; ++mr)
            af[mr] = *(const bf16x8*)&sXt[mr * 16 + n16][g * 8];
        #pragma unroll
        for (int nc = 0; nc < 4; ++nc)
            bfr[nc] = *(const bf16x8*)&sW[wv * 64 + nc * 16 + n16][g * 8];
        #pragma unroll
        for (int mr = 0; mr < 4; ++mr)
            #pragma unroll
            for (int nc = 0; nc < 4; ++nc)
                acc[mr][nc] = __builtin_amdgcn_mfma_f32_16x16x32_bf16(
                    af[mr], bfr[nc], acc[mr][nc], 0, 0, 0);
    }

    // D fragment: row l = mr*16 + g*4 + r, col i = nc*16 + n16 (+wv*64)
    if (which == 0) {
        __bf16* out = Q + (size_t)b * LSEQ * DIN;
        #pragma unroll
        for (int nc = 0; nc < 4; ++nc) {
            const int icol = wv * 64 + nc * 16 + n16;
            const float bb = bias[icol];
            #pragma unroll
            for (int mr = 0; mr < 4; ++mr) {
                const int lrow = l0 + mr * 16 + g * 4;
                #pragma unroll
                for (int r = 0; r < 4; ++r)
                    out[(size_t)(lrow + r) * DIN + icol] = (__bf16)(acc[mr][nc][r] + bb);
            }
        }
    } else if (which == 1) {
        #pragma unroll
        for (int nc = 0; nc < 4; ++nc) {
            const int icol = wv * 64 + nc * 16 + n16;
            const float bb = bias[icol];
            #pragma unroll
            for (int mr = 0; mr < 4; ++mr) {
                #pragma unroll
                for (int r = 0; r < 4; ++r) {
                    const int lrow = l0 + mr * 16 + g * 4 + r;
                    const int t2 = lrow >> 5, row = lrow & 31;
                    const size_t off = ((size_t)(b * NT2 + t2) << 15)
                                     + (size_t)row * 512
                                     + ((icol * 2) ^ ((row & 7) << 4));
                    *(__bf16*)(KV + off) = (__bf16)(acc[mr][nc][r] + bb);
                }
            }
        }
    } else {
        #pragma unroll
        for (int nc = 0; nc < 4; ++nc) {
            const int d  = wv * 64 + nc * 16 + n16;
            const float bb = bias[d];
            #pragma unroll
            for (int mr = 0; mr < 4; ++mr) {
                const int lrow = l0 + mr * 16 + g * 4;   // 4 consecutive l (8B run)
                const int t2 = lrow >> 5, c = lrow & 31;
                bf16x4 pk;
                #pragma unroll
                for (int r = 0; r < 4; ++r)
                    pk[r] = (__bf16)(acc[mr][nc][r] + bb);
                const size_t off = ((size_t)(b * NT2 + t2) << 15) + 16384
                                 + (size_t)(d >> 1) * 128
                                 + ((((d & 1) * 64) + 2 * c) ^ (((d >> 1) & 7) << 4));
                *(bf16x4*)(KV + off) = pk;
            }
        }
    }
}

// ---------------------------------------------------------------------------
// Kernel 2: flash attention v4 — de-lockstepped.
// 256 threads = 4 waves; Q-tile 64 (16 rows/wave, 1 m-frag). KV tile 32 rows.
// LDS 68KB -> 2 INDEPENDENT blocks/CU (no shared barriers) so the 2 waves on
// each SIMD are at random phase offsets and hide each other's stalls
// (R2->R3 A/B showed same-block waves in barrier lockstep gain nothing).
// Defer-max (T13): skip O-rescale while __all(rmax - m <= 88.7) (=8 folded
// units; P<=256, exact online softmax with lagged max).
// Pre-swizzled KV tile images staged via global_load_lds, dbuf, counted vmcnt.
// Grid (b=8, qt=64): id%8==b -> one batch per XCD, KV L2-resident.
// ---------------------------------------------------------------------------
__global__ __launch_bounds__(256) void attn_kernel(
    const __bf16* __restrict__ Q, const uint8_t* __restrict__ KV,
    __bf16* __restrict__ O)
{
    const int b   = blockIdx.x;
    const int q0  = blockIdx.y * 64;
    const int tid = threadIdx.x;
    const int wv  = tid >> 6, lane = tid & 63, g = lane >> 4, n16 = lane & 15;

    __shared__ __align__(1024) uint8_t sKV[2][32768];  // dbuf 32-row KV tiles
    __shared__ __align__(1024) uint8_t sP[4096];       // P [64 q][32 kj], pair-swizzled

    // Q fragments: 1 m-frag x 8 k-slices, row q0 + wv*16 + n16
    bf16x8 qf[8];
    {
        const __bf16* Qrow = Q + ((size_t)b * LSEQ + q0 + wv * 16 + n16) * DIN;
        #pragma unroll
        for (int ks = 0; ks < 8; ++ks)
            qf[ks] = *(const bf16x8*)(Qrow + ks * 32 + g * 8);
    }

    float m_i[4], l_i[4];
    #pragma unroll
    for (int r = 0; r < 4; ++r) { m_i[r] = -__builtin_inff(); l_i[r] = 0.f; }
    f32x4 accO[16];
    #pragma unroll
    for (int ds = 0; ds < 16; ++ds) accO[ds] = f32x4{0.f, 0.f, 0.f, 0.f};

    const uint8_t* KVb = KV + ((size_t)b * NT2 << 15);
    const float CEXP = 1.4426950408889634f / 16.0f;   // log2(e)/scale, scale=16
    const float DEFER_TH = 88.7f;                     // 8 / CEXP

    // prologue: stage tile 0 (256 thr x 16B x 8 = 32KB)
    #pragma unroll
    for (int p = 0; p < 8; ++p) {
        const int off = p * 4096 + tid * 16;
        gload_lds16(KVb + off, &sKV[0][off]);
    }

    for (int t = 0; t < NT2; ++t) {
        const int buf = t & 1;
        if (t + 1 < NT2) {
            const uint8_t* src = KVb + ((size_t)(t + 1) << 15);
            #pragma unroll
            for (int p = 0; p < 8; ++p) {
                const int off = p * 4096 + tid * 16;
                gload_lds16(src + off, &sKV[buf ^ 1][off]);
            }
            asm volatile("s_waitcnt vmcnt(8)" ::: "memory");  // cur tile done, next in flight
        } else {
            asm volatile("s_waitcnt vmcnt(0)" ::: "memory");
        }
        __builtin_amdgcn_s_barrier();
        asm volatile("" ::: "memory");

        const uint8_t* kb = sKV[buf];

        // ---- QK^T: D[qi][kj], 32 kj (2 nc frags), K=256 over 8 ks ----
        f32x4 sacc[2];
        sacc[0] = f32x4{0.f, 0.f, 0.f, 0.f};
        sacc[1] = f32x4{0.f, 0.f, 0.f, 0.f};
        #pragma unroll
        for (int ks = 0; ks < 8; ++ks) {
            #pragma unroll
            for (int nc = 0; nc < 2; ++nc) {
                const int row = nc * 16 + n16;
                const bf16x8 kf = *(const bf16x8*)(kb + row * 512
                                   + ((ks * 64 + g * 16) ^ ((row & 7) << 4)));
                sacc[nc] = __builtin_amdgcn_mfma_f32_16x16x32_bf16(qf[ks], kf, sacc[nc], 0, 0, 0);
            }
        }

        // ---- online softmax with defer-max; lane rows g*4+r ----
        float rmax[4];
        float worst = -__builtin_inff();
        #pragma unroll
        for (int r = 0; r < 4; ++r) {
            float mx = fmaxf(sacc[0][r], sacc[1][r]);
            mx = fmaxf(mx, __shfl_xor(mx, 1));
            mx = fmaxf(mx, __shfl_xor(mx, 2));
            mx = fmaxf(mx, __shfl_xor(mx, 4));
            mx = fmaxf(mx, __shfl_xor(mx, 8));
            rmax[r] = mx;
            worst = fmaxf(worst, mx - m_i[r]);
        }
        if (!__all(worst <= DEFER_TH)) {
            float scl[4];
            #pragma unroll
            for (int r = 0; r < 4; ++r) {
                const float mnew = fmaxf(m_i[r], rmax[r]);
                scl[r] = exp2f((m_i[r] - mnew) * CEXP);
                l_i[r] *= scl[r];
                m_i[r] = mnew;
            }
            #pragma unroll
            for (int ds = 0; ds < 16; ++ds)
                #pragma unroll
                for (int r = 0; r < 4; ++r)
                    accO[ds][r] *= scl[r];
        }
        #pragma unroll
        for (int r = 0; r < 4; ++r) {
            const float pv0 = exp2f((sacc[0][r] - m_i[r]) * CEXP);
            const float pv1 = exp2f((sacc[1][r] - m_i[r]) * CEXP);
            sacc[0][r] = pv0;
            sacc[1][r] = pv1;
            float rsum = pv0 + pv1;
            rsum += __shfl_xor(rsum, 1);
            rsum += __shfl_xor(rsum, 2);
            rsum += __shfl_xor(rsum, 4);
            rsum += __shfl_xor(rsum, 8);
            l_i[r] += rsum;
        }

        // ---- P -> LDS (wave-private rows; pair-swizzled 128B rows) ----
        #pragma unroll
        for (int r = 0; r < 4; ++r) {
            const int row = wv * 16 + g * 4 + r;
            #pragma unroll
            for (int nc = 0; nc < 2; ++nc) {
                const int col = nc * 16 + n16;
                const int off = (row >> 1) * 128
                              + ((((row & 1) * 64) + 2 * col) ^ (((row >> 1) & 7) << 4));
                *(__bf16*)(sP + off) = (__bf16)sacc[nc][r];
            }
        }

        // ---- PV: A = P row (n16), B = V pair-swizzled img ----
        bf16x8 af;
        {
            const int row = wv * 16 + n16;
            af = *(const bf16x8*)(sP + (row >> 1) * 128
                   + ((((row & 1) * 64) + g * 16) ^ (((row >> 1) & 7) << 4)));
        }
        #pragma unroll
        for (int ds = 0; ds < 16; ++ds) {
            const int d = ds * 16 + n16;
            const bf16x8 vf = *(const bf16x8*)(kb + 16384 + (d >> 1) * 128
                               + ((((d & 1) * 64) + g * 16) ^ (((d >> 1) & 7) << 4)));
            accO[ds] = __builtin_amdgcn_mfma_f32_16x16x32_bf16(af, vf, accO[ds], 0, 0, 0);
        }

        asm volatile("" ::: "memory");
        __builtin_amdgcn_s_barrier();   // all waves done reading buf before overwrite
    }

    // ---- epilogue: O[l][d] = accO / l_i ----
    float inv[4];
    #pragma unroll
    for (int r = 0; r < 4; ++r) inv[r] = 1.f / l_i[r];
    __bf16* Ob = O + ((size_t)b * LSEQ + q0 + wv * 16) * DIN;
    #pragma unroll
    for (int ds = 0; ds < 16; ++ds)
        #pragma unroll
        for (int r = 0; r < 4; ++r)
            Ob[(size_t)(g * 4 + r) * DIN + ds * 16 + n16] = (__bf16)(accO[ds][r] * inv[r]);
}

// ---------------------------------------------------------------------------
// Kernel 3: output projection. out[b][c][l] = sum_i Wo[c][i]*O[b][l][i] + bo[c].
// ---------------------------------------------------------------------------
__global__ __launch_bounds__(256) void out_proj_kernel(
    const float* __restrict__ Wo, const float* __restrict__ bo,
    const __bf16* __restrict__ O, float* __restrict__ out)
{
    const int b   = blockIdx.z;
    const int c0  = blockIdx.y * 64;
    const int l0  = blockIdx.x * 256;
    const int tid = threadIdx.x;
    const int wv  = tid >> 6, lane = tid & 63, g = lane >> 4, n16 = lane & 15;

    __shared__ __align__(16) __bf16 sWo[64][40];   // [c][i]
    __shared__ __align__(16) __bf16 sO[256][40];   // [l][i]

    const __bf16* Ob = O + (size_t)b * LSEQ * DIN;

    f32x4 acc[4][4];
    #pragma unroll
    for (int i = 0; i < 4; ++i)
        #pragma unroll
        for (int j = 0; j < 4; ++j)
            acc[i][j] = f32x4{0.f, 0.f, 0.f, 0.f};

    for (int kk = 0; kk < 8; ++kk) {
        const int i0 = kk * 32;
        __syncthreads();
        #pragma unroll
        for (int p = 0; p < 2; ++p) {
            const int c  = p * 32 + (tid >> 3);
            const int i4 = (tid & 7) * 4;
            const float4 v = *(const float4*)(Wo + (size_t)(c0 + c) * DIN + i0 + i4);
            bf16x4 pk = { (__bf16)v.x, (__bf16)v.y, (__bf16)v.z, (__bf16)v.w };
            *(bf16x4*)&sWo[c][i4] = pk;
        }
        #pragma unroll
        for (int p = 0; p < 4; ++p) {
            const int l  = p * 64 + (tid >> 2);
            const int sg = tid & 3;
            *(uint4*)&sO[l][sg * 8] = *(const uint4*)(Ob + (size_t)(l0 + l) * DIN + i0 + sg * 8);
        }
        __syncthreads();

        bf16x8 af[4], bfr[4];
        #pragma unroll
        for (int mr = 0; mr < 4; ++mr)
            af[mr] = *(const bf16x8*)&sWo[mr * 16 + n16][g * 8];
        #pragma unroll
        for (int nc = 0; nc < 4; ++nc)
            bfr[nc] = *(const bf16x8*)&sO[wv * 64 + nc * 16 + n16][g * 8];
        #pragma unroll
        for (int mr = 0; mr < 4; ++mr)
            #pragma unroll
            for (int nc = 0; nc < 4; ++nc)
                acc[mr][nc] = __builtin_amdgcn_mfma_f32_16x16x32_bf16(
                    af[mr], bfr[nc], acc[mr][nc], 0, 0, 0);
    }

    #pragma unroll
    for (int mr = 0; mr < 4; ++mr) {
        const int c = c0 + mr * 16 + g * 4;
        #pragma unroll
        for (int nc = 0; nc < 4; ++nc) {
            const int l = l0 + wv * 64 + nc * 16 + n16;
            #pragma unroll
            for (int r = 0; r < 4; ++r)
                out[((size_t)b * CH + c + r) * LSEQ + l] = acc[mr][nc][r] + bo[c + r];
        }
    }
}

// ---------------------------------------------------------------------------
extern "C" void kernel_launch(void* const* d_in, const int* in_sizes, int n_in,
                              void* d_out, int out_size, void* d_ws, size_t ws_size,
                              hipStream_t stream)
{
    const float* x  = (const float*)d_in[0];
    const float* Wq = (const float*)d_in[1];
    const float* bq = (const float*)d_in[2];
    const float* Wk = (const float*)d_in[3];
    const float* bk = (const float*)d_in[4];
    const float* Wv = (const float*)d_in[5];
    const float* bv = (const float*)d_in[6];
    const float* Wo = (const float*)d_in[7];
    const float* bo = (const float*)d_in[8];
    float* out = (float*)d_out;

    // ws: Q bf16 16MB | KV swizzled tile images 32MB | O bf16 16MB = 64MB
    __bf16*  Q  = (__bf16*)d_ws;
    uint8_t* KV = (uint8_t*)d_ws + (16u << 20);
    __bf16*  O  = (__bf16*)((uint8_t*)d_ws + (48u << 20));

    qkv_proj_kernel<<<dim3(LSEQ / 64, 3, BS), 256, 0, stream>>>(
        x, Wq, bq, Wk, bk, Wv, bv, Q, KV);
    attn_kernel<<<dim3(BS, LSEQ / 64), 256, 0, stream>>>(Q, KV, O);
    out_proj_kernel<<<dim3(LSEQ / 256, CH / 64, BS), 256, 0, stream>>>(Wo, bo, O, out);
}